// Round 1
// baseline (27341.937 us; speedup 1.0000x reference)
//
#include <hip/hip_runtime.h>
#include <hip/hip_bf16.h>

#define S_ 512
#define B_ 32
#define D_ 512
#define H_ 8
#define L_ 6
#define DFF_ 1024
#define M_ (B_*S_)   // 16384 rows

// ---------------------------------------------------------------------------
// LayerNorm: one wave per row of 512 floats.
__global__ __launch_bounds__(256) void ln_kernel(const float* __restrict__ in,
    float* __restrict__ out, const float* __restrict__ g, const float* __restrict__ b)
{
  int row  = (blockIdx.x << 2) + (threadIdx.x >> 6);
  int lane = threadIdx.x & 63;
  const float* r = in + (size_t)row * D_;
  float4 v0 = *(const float4*)(r + lane * 4);
  float4 v1 = *(const float4*)(r + 256 + lane * 4);
  float s = v0.x + v0.y + v0.z + v0.w + v1.x + v1.y + v1.z + v1.w;
  #pragma unroll
  for (int m = 1; m < 64; m <<= 1) s += __shfl_xor(s, m);
  float mean = s * (1.0f / 512.0f);
  float a0 = v0.x - mean, a1 = v0.y - mean, a2 = v0.z - mean, a3 = v0.w - mean;
  float a4 = v1.x - mean, a5 = v1.y - mean, a6 = v1.z - mean, a7 = v1.w - mean;
  float sq = a0*a0 + a1*a1 + a2*a2 + a3*a3 + a4*a4 + a5*a5 + a6*a6 + a7*a7;
  #pragma unroll
  for (int m = 1; m < 64; m <<= 1) sq += __shfl_xor(sq, m);
  float inv = rsqrtf(sq * (1.0f / 512.0f) + 1e-5f);
  float4 g0 = *(const float4*)(g + lane * 4);
  float4 g1 = *(const float4*)(g + 256 + lane * 4);
  float4 b0 = *(const float4*)(b + lane * 4);
  float4 b1 = *(const float4*)(b + 256 + lane * 4);
  float* o = out + (size_t)row * D_;
  float4 o0 = make_float4(a0*inv*g0.x + b0.x, a1*inv*g0.y + b0.y,
                          a2*inv*g0.z + b0.z, a3*inv*g0.w + b0.w);
  float4 o1 = make_float4(a4*inv*g1.x + b1.x, a5*inv*g1.y + b1.y,
                          a6*inv*g1.z + b1.z, a7*inv*g1.w + b1.w);
  *(float4*)(o + lane * 4) = o0;
  *(float4*)(o + 256 + lane * 4) = o1;
}

// ---------------------------------------------------------------------------
// Generic f32 GEMM:  C[M,N] = epi(A[M,K] @ W[N,K]^T + bias[N])
// EPI: 0 = store, 1 = relu+store, 2 = C += result (residual)
template<int EPI>
__global__ __launch_bounds__(256) void gemm_nt(const float* __restrict__ A,
    const float* __restrict__ W, const float* __restrict__ bias,
    float* __restrict__ C, int M, int N, int K)
{
  __shared__ __align__(16) float As[16][68];
  __shared__ __align__(16) float Ws[16][68];
  const int tid  = threadIdx.x;
  const int row0 = blockIdx.y << 6, col0 = blockIdx.x << 6;
  const int tx = tid & 15, ty = tid >> 4;
  const int lr = tid >> 2, lc = (tid & 3) << 2;
  const float* Ap = A + (size_t)(row0 + lr) * K + lc;
  const float* Wp = W + (size_t)(col0 + lr) * K + lc;
  float acc[4][4] = {};
  for (int k0 = 0; k0 < K; k0 += 16) {
    float4 av = *(const float4*)(Ap + k0);
    float4 wv = *(const float4*)(Wp + k0);
    __syncthreads();
    As[lc+0][lr] = av.x; As[lc+1][lr] = av.y; As[lc+2][lr] = av.z; As[lc+3][lr] = av.w;
    Ws[lc+0][lr] = wv.x; Ws[lc+1][lr] = wv.y; Ws[lc+2][lr] = wv.z; Ws[lc+3][lr] = wv.w;
    __syncthreads();
    #pragma unroll
    for (int kk = 0; kk < 16; kk++) {
      float4 a  = *(const float4*)&As[kk][ty << 2];
      float4 bb = *(const float4*)&Ws[kk][tx << 2];
      acc[0][0] += a.x*bb.x; acc[0][1] += a.x*bb.y; acc[0][2] += a.x*bb.z; acc[0][3] += a.x*bb.w;
      acc[1][0] += a.y*bb.x; acc[1][1] += a.y*bb.y; acc[1][2] += a.y*bb.z; acc[1][3] += a.y*bb.w;
      acc[2][0] += a.z*bb.x; acc[2][1] += a.z*bb.y; acc[2][2] += a.z*bb.z; acc[2][3] += a.z*bb.w;
      acc[3][0] += a.w*bb.x; acc[3][1] += a.w*bb.y; acc[3][2] += a.w*bb.z; acc[3][3] += a.w*bb.w;
    }
  }
  float4 bv = *(const float4*)(bias + col0 + (tx << 2));
  #pragma unroll
  for (int i = 0; i < 4; i++) {
    float* cp = C + (size_t)(row0 + (ty << 2) + i) * N + col0 + (tx << 2);
    float4 val = make_float4(acc[i][0] + bv.x, acc[i][1] + bv.y,
                             acc[i][2] + bv.z, acc[i][3] + bv.w);
    if (EPI == 1) {
      val.x = fmaxf(val.x, 0.f); val.y = fmaxf(val.y, 0.f);
      val.z = fmaxf(val.z, 0.f); val.w = fmaxf(val.w, 0.f);
    }
    if (EPI == 2) {
      float4 c0 = *(const float4*)cp;
      val.x += c0.x; val.y += c0.y; val.z += c0.z; val.w += c0.w;
    }
    *(float4*)cp = val;
  }
}

// ---------------------------------------------------------------------------
// Embedding GEMM with gathered A rows:
//   h[m, n] = sum_k arg_emb[args[s,b, k/128]][k%128] * embed_fcn_w[n][k] + bias[n]
// m = b*512 + s; K=1024, N=512.
__global__ __launch_bounds__(256) void gemm_embed(const int* __restrict__ x,
    const float* __restrict__ arg_emb, const float* __restrict__ W,
    const float* __restrict__ bias, float* __restrict__ C)
{
  __shared__ __align__(16) float As[16][68];
  __shared__ __align__(16) float Ws[16][68];
  const int tid  = threadIdx.x;
  const int row0 = blockIdx.y << 6, col0 = blockIdx.x << 6;
  const int tx = tid & 15, ty = tid >> 4;
  const int lr = tid >> 2, lc = (tid & 3) << 2;
  const int m = row0 + lr, b = m >> 9, s = m & 511;
  const int* argrow = x + (size_t)(s * B_ + b) * 9 + 1;
  int aidx[8];
  #pragma unroll
  for (int j = 0; j < 8; j++) aidx[j] = argrow[j];
  const float* Wp = W + (size_t)(col0 + lr) * 1024 + lc;
  float acc[4][4] = {};
  for (int k0 = 0; k0 < 1024; k0 += 16) {
    int kk_ = k0 + lc;
    float4 av = *(const float4*)(arg_emb + aidx[kk_ >> 7] * 128 + (kk_ & 127));
    float4 wv = *(const float4*)(Wp + k0);
    __syncthreads();
    As[lc+0][lr] = av.x; As[lc+1][lr] = av.y; As[lc+2][lr] = av.z; As[lc+3][lr] = av.w;
    Ws[lc+0][lr] = wv.x; Ws[lc+1][lr] = wv.y; Ws[lc+2][lr] = wv.z; Ws[lc+3][lr] = wv.w;
    __syncthreads();
    #pragma unroll
    for (int kk = 0; kk < 16; kk++) {
      float4 a  = *(const float4*)&As[kk][ty << 2];
      float4 bb = *(const float4*)&Ws[kk][tx << 2];
      acc[0][0] += a.x*bb.x; acc[0][1] += a.x*bb.y; acc[0][2] += a.x*bb.z; acc[0][3] += a.x*bb.w;
      acc[1][0] += a.y*bb.x; acc[1][1] += a.y*bb.y; acc[1][2] += a.y*bb.z; acc[1][3] += a.y*bb.w;
      acc[2][0] += a.z*bb.x; acc[2][1] += a.z*bb.y; acc[2][2] += a.z*bb.z; acc[2][3] += a.z*bb.w;
      acc[3][0] += a.w*bb.x; acc[3][1] += a.w*bb.y; acc[3][2] += a.w*bb.z; acc[3][3] += a.w*bb.w;
    }
  }
  float4 bv = *(const float4*)(bias + col0 + (tx << 2));
  #pragma unroll
  for (int i = 0; i < 4; i++) {
    float* cp = C + (size_t)(row0 + (ty << 2) + i) * D_ + col0 + (tx << 2);
    *(float4*)cp = make_float4(acc[i][0] + bv.x, acc[i][1] + bv.y,
                               acc[i][2] + bv.z, acc[i][3] + bv.w);
  }
}

// ---------------------------------------------------------------------------
// Finish embedding: h += cmd_emb[cmd] + pos_enc(s);  row s==0 := cls_emb[trg_char[b]]
__global__ __launch_bounds__(128) void embed_finish(float* __restrict__ h,
    const int* __restrict__ x, const float* __restrict__ cmd_emb,
    const float* __restrict__ cls_emb, const int* __restrict__ trg_char)
{
  int m = blockIdx.x, b = m >> 9, s = m & 511;
  int d = threadIdx.x << 2;
  float4* hp = (float4*)(h + (size_t)m * D_ + d);
  if (s == 0) {
    int c = trg_char[b];
    *hp = *(const float4*)(cls_emb + (size_t)c * D_ + d);
  } else {
    int cmd = x[(size_t)(s * B_ + b) * 9];
    float4 v  = *hp;
    float4 ce = *(const float4*)(cmd_emb + (size_t)cmd * D_ + d);
    const float kfac = -0.017988946039f;   // -ln(10000)/512
    int i0 = d >> 1;
    float ang0 = (float)s * expf((float)(2 * i0) * kfac);
    float ang1 = (float)s * expf((float)(2 * (i0 + 1)) * kfac);
    v.x += ce.x + sinf(ang0);
    v.y += ce.y + cosf(ang0);
    v.z += ce.z + sinf(ang1);
    v.w += ce.w + cosf(ang1);
    *hp = v;
  }
}

// ---------------------------------------------------------------------------
// Causal attention, one wave per (b, h, q) row.  o may alias q (own-row only).
// WP: also write normalized probabilities (two-pass).
template<bool WP>
__global__ __launch_bounds__(256) void attn_fwd(const float* __restrict__ kb,
    const float* __restrict__ vb, const float* qb, float* ob, float* __restrict__ pout)
{
  int wid  = (blockIdx.x << 2) + (threadIdx.x >> 6);
  int lane = threadIdx.x & 63;
  int b  = wid >> 12;            // H*S = 4096
  int hh = (wid >> 9) & 7;
  int qq = wid & 511;
  size_t rowoff = ((size_t)(b * S_ + qq)) * D_ + hh * 64 + lane;
  size_t base   = ((size_t)(b * S_)) * D_ + hh * 64 + lane;
  float qv = qb[rowoff];
  const float* kr = kb + base;
  const float* vr = vb + base;
  if (!WP) {
    float m = -1e30f, lsum = 0.f, oacc = 0.f;
    for (int kk = 0; kk <= qq; kk++) {
      float part = qv * kr[(size_t)kk * D_];
      #pragma unroll
      for (int mm = 1; mm < 64; mm <<= 1) part += __shfl_xor(part, mm);
      float sc = part * 0.125f;
      if (sc > m) { float c = __expf(m - sc); oacc *= c; lsum *= c; m = sc; }
      float p = __expf(sc - m);
      lsum += p;
      oacc += p * vr[(size_t)kk * D_];
    }
    ob[rowoff] = oacc / lsum;
  } else {
    float m = -1e30f, lsum = 0.f;
    for (int kk = 0; kk <= qq; kk++) {
      float part = qv * kr[(size_t)kk * D_];
      #pragma unroll
      for (int mm = 1; mm < 64; mm <<= 1) part += __shfl_xor(part, mm);
      float sc = part * 0.125f;
      if (sc > m) { lsum *= __expf(m - sc); m = sc; }
      lsum += __expf(sc - m);
    }
    float inv = 1.0f / lsum;
    float oacc = 0.f;
    float* prow = pout + ((size_t)((b * H_ + hh) * S_ + qq)) * S_;
    for (int c = 0; c < 8; c++) {
      float preg = 0.f;
      int k0 = c << 6, k1 = (k0 + 63 < qq) ? k0 + 63 : qq;
      for (int kk = k0; kk <= k1; kk++) {
        float part = qv * kr[(size_t)kk * D_];
        #pragma unroll
        for (int mm = 1; mm < 64; mm <<= 1) part += __shfl_xor(part, mm);
        float p = __expf(part * 0.125f - m) * inv;
        oacc += p * vr[(size_t)kk * D_];
        if ((kk & 63) == lane) preg = p;
      }
      prow[k0 + lane] = preg;   // zeros above diagonal included
    }
    ob[rowoff] = oacc;
  }
}

// ---------------------------------------------------------------------------
// Cross-attention precompute (softmax over single key == 1):
//   vvec[l,b,:] = mem[b] @ ca_w[l,2].T + ca_b[l,2]
//   ca_out[l,b,:] = vvec[l,b] @ ca_w[l,3].T + ca_b[l,3]
__global__ __launch_bounds__(256) void ca_stage(const float* __restrict__ in,
    const float* __restrict__ ca_w, const float* __restrict__ ca_b,
    float* __restrict__ outb, int wsel, int in_is_per_l)
{
  int l = blockIdx.x >> 5, b = blockIdx.x & 31;
  __shared__ float sm[512];
  const float* src = in_is_per_l ? in + ((size_t)l * 32 + b) * 512 : in + (size_t)b * 512;
  for (int i = threadIdx.x; i < 512; i += 256) sm[i] = src[i];
  __syncthreads();
  const float* Wl = ca_w + ((size_t)(l * 4 + wsel)) * 512 * 512;
  const float* bl = ca_b + (l * 4 + wsel) * 512;
  for (int n = threadIdx.x; n < 512; n += 256) {
    const float* wr = Wl + (size_t)n * 512;
    float acc = 0.f;
    for (int k2 = 0; k2 < 512; k2 += 4) {
      float4 w4 = *(const float4*)(wr + k2);
      acc += sm[k2] * w4.x + sm[k2+1] * w4.y + sm[k2+2] * w4.z + sm[k2+3] * w4.w;
    }
    outb[((size_t)l * 32 + b) * 512 + n] = acc + bl[n];
  }
}

// h[b,s,:] += ca_out_l[b,:]
__global__ __launch_bounds__(128) void add_ca(float* __restrict__ h,
    const float* __restrict__ ca)
{
  int m = blockIdx.x, b = m >> 9;
  int d = threadIdx.x << 2;
  float4* hp = (float4*)(h + (size_t)m * D_ + d);
  float4 v = *hp;
  float4 c = *(const float4*)(ca + (size_t)b * D_ + d);
  v.x += c.x; v.y += c.y; v.z += c.z; v.w += c.w;
  *hp = v;
}

// cmd head: (16384,512) @ (4,512)^T + cmd_b
__global__ __launch_bounds__(256) void cmd_head(const float* __restrict__ xn,
    const float* __restrict__ cw, const float* __restrict__ cb, float* __restrict__ out)
{
  int row  = (blockIdx.x << 2) + (threadIdx.x >> 6);
  int lane = threadIdx.x & 63;
  const float* r = xn + (size_t)row * D_ + lane * 8;
  float4 x0 = *(const float4*)r, x1 = *(const float4*)(r + 4);
  #pragma unroll
  for (int n = 0; n < 4; n++) {
    const float* w = cw + n * 512 + lane * 8;
    float4 w0 = *(const float4*)w, w1 = *(const float4*)(w + 4);
    float p = x0.x*w0.x + x0.y*w0.y + x0.z*w0.z + x0.w*w0.w
            + x1.x*w1.x + x1.y*w1.y + x1.z*w1.z + x1.w*w1.w;
    #pragma unroll
    for (int m = 1; m < 64; m <<= 1) p += __shfl_xor(p, m);
    if (lane == 0) out[(size_t)row * 4 + n] = p + cb[n];
  }
}

// ---------------------------------------------------------------------------
extern "C" void kernel_launch(void* const* d_in, const int* in_sizes, int n_in,
                              void* d_out, int out_size, void* d_ws, size_t ws_size,
                              hipStream_t stream)
{
  const int*   x          = (const int*)  d_in[0];
  const float* memory     = (const float*)d_in[1];
  const int*   trg_char   = (const int*)  d_in[2];
  // d_in[3] tgt_mask: exactly tril -> causal, unused
  const float* cmd_emb    = (const float*)d_in[4];
  const float* arg_emb    = (const float*)d_in[5];
  const float* embed_w    = (const float*)d_in[6];
  const float* embed_b    = (const float*)d_in[7];
  const float* sa_w       = (const float*)d_in[8];
  const float* sa_b       = (const float*)d_in[9];
  const float* ca_w       = (const float*)d_in[10];
  const float* ca_b       = (const float*)d_in[11];
  const float* ff_w1      = (const float*)d_in[12];
  const float* ff_b1      = (const float*)d_in[13];
  const float* ff_w2      = (const float*)d_in[14];
  const float* ff_b2      = (const float*)d_in[15];
  const float* ln_g       = (const float*)d_in[16];
  const float* ln_b       = (const float*)d_in[17];
  const float* fn_g       = (const float*)d_in[18];
  const float* fn_b       = (const float*)d_in[19];
  const float* cls_emb    = (const float*)d_in[20];
  const float* cmd_w      = (const float*)d_in[21];
  const float* cmd_b      = (const float*)d_in[22];
  const float* argf_w     = (const float*)d_in[23];
  const float* argf_b     = (const float*)d_in[24];

  float* out_cmd  = (float*)d_out;                       // (B,S,4)
  float* out_args = out_cmd + (size_t)M_ * 4;            // (B,S,1024)
  float* out_attn = out_args + (size_t)M_ * 1024;        // (B,H,S,S)

  const size_t MS = (size_t)M_ * D_;                     // 8388608 floats
  float* ws     = (float*)d_ws;
  float* h      = ws;
  float* xn     = ws + MS;
  float* qo     = ws + 2 * MS;       // q, later aliased by attention output o
  float* kbuf   = ws + 3 * MS;
  float* vbuf   = ws + 4 * MS;
  float* t      = ws + 5 * MS;       // FF intermediate (2*MS floats)
  float* vvec   = ws + 7 * MS;       // 6*32*512
  float* ca_out = vvec + 6 * 32 * 512;

  dim3 blk256(256), blk128(128);
  dim3 g_gemm512(D_ / 64, M_ / 64);        // (8, 256)
  dim3 g_gemm1024(DFF_ / 64, M_ / 64);     // (16, 256)
  dim3 g_ln(M_ / 4);
  dim3 g_attn((size_t)B_ * H_ * S_ / 4);   // 32768
  dim3 g_row(M_);

  // Cross-attention precompute (tiny)
  ca_stage<<<dim3(L_ * 32), blk256, 0, stream>>>(memory, ca_w, ca_b, vvec, 2, 0);
  ca_stage<<<dim3(L_ * 32), blk256, 0, stream>>>(vvec, ca_w, ca_b, ca_out, 3, 1);

  // Embedding
  gemm_embed<<<g_gemm512, blk256, 0, stream>>>(x, arg_emb, embed_w, embed_b, h);
  embed_finish<<<g_row, blk128, 0, stream>>>(h, x, cmd_emb, cls_emb, trg_char);

  for (int l = 0; l < L_; l++) {
    const float* saW = sa_w + (size_t)l * 4 * D_ * D_;
    const float* saB = sa_b + (size_t)l * 4 * D_;
    // LN 0 -> xn
    ln_kernel<<<g_ln, blk256, 0, stream>>>(h, xn, ln_g + (l * 3 + 0) * D_, ln_b + (l * 3 + 0) * D_);
    // q,k,v projections
    gemm_nt<0><<<g_gemm512, blk256, 0, stream>>>(xn, saW,              saB,          qo,   M_, D_, D_);
    gemm_nt<0><<<g_gemm512, blk256, 0, stream>>>(xn, saW + (size_t)D_*D_,   saB + D_,   kbuf, M_, D_, D_);
    gemm_nt<0><<<g_gemm512, blk256, 0, stream>>>(xn, saW + (size_t)2*D_*D_, saB + 2*D_, vbuf, M_, D_, D_);
    // attention (o aliases q)
    if (l == L_ - 1)
      attn_fwd<true><<<g_attn, blk256, 0, stream>>>(kbuf, vbuf, qo, qo, out_attn);
    else
      attn_fwd<false><<<g_attn, blk256, 0, stream>>>(kbuf, vbuf, qo, qo, nullptr);
    // output projection, residual into h
    gemm_nt<2><<<g_gemm512, blk256, 0, stream>>>(qo, saW + (size_t)3*D_*D_, saB + 3*D_, h, M_, D_, D_);
    // cross-attention broadcast add
    add_ca<<<g_row, blk128, 0, stream>>>(h, ca_out + (size_t)l * 32 * D_);
    // LN 2 -> xn, FF
    ln_kernel<<<g_ln, blk256, 0, stream>>>(h, xn, ln_g + (l * 3 + 2) * D_, ln_b + (l * 3 + 2) * D_);
    gemm_nt<1><<<g_gemm1024, blk256, 0, stream>>>(xn, ff_w1 + (size_t)l*DFF_*D_, ff_b1 + l*DFF_, t, M_, DFF_, D_);
    gemm_nt<2><<<g_gemm512,  blk256, 0, stream>>>(t,  ff_w2 + (size_t)l*D_*DFF_, ff_b2 + l*D_,   h, M_, D_, DFF_);
  }

  // Final LN + heads
  ln_kernel<<<g_ln, blk256, 0, stream>>>(h, xn, fn_g, fn_b);
  gemm_nt<0><<<g_gemm1024, blk256, 0, stream>>>(xn, argf_w, argf_b, out_args, M_, 1024, D_);
  cmd_head<<<dim3(M_ / 4), blk256, 0, stream>>>(xn, cmd_w, cmd_b, out_cmd);
}

// Round 2
// 5478.661 us; speedup vs baseline: 4.9906x; 4.9906x over previous
//
#include <hip/hip_runtime.h>
#include <hip/hip_bf16.h>

#define S_ 512
#define B_ 32
#define D_ 512
#define H_ 8
#define L_ 6
#define DFF_ 1024
#define M_ (B_*S_)   // 16384 rows

typedef __attribute__((ext_vector_type(8))) short bf16x8;
typedef __attribute__((ext_vector_type(4))) float f32x4;

__device__ __forceinline__ ushort f2bf(float f) {
  union { float f; unsigned int u; } x; x.f = f;
  unsigned int r = x.u + 0x7fffu + ((x.u >> 16) & 1u);
  return (ushort)(r >> 16);
}
__device__ __forceinline__ float bf2f(unsigned int u) {
  union { unsigned int u; float f; } x; x.u = u << 16;
  return x.f;
}

__device__ __forceinline__ void gload16(const ushort* g, ushort* l) {
  __builtin_amdgcn_global_load_lds(
      (const __attribute__((address_space(1))) unsigned int*)g,
      (__attribute__((address_space(3))) unsigned int*)l, 16, 0, 0);
}

// ---------------------------------------------------------------------------
// f32 -> bf16 bulk convert (n8 = n/8 threads, 8 elems each)
__global__ __launch_bounds__(256) void cvt_bf16(const float* __restrict__ in,
    ushort* __restrict__ out, int n8)
{
  int t = blockIdx.x * 256 + threadIdx.x;
  if (t >= n8) return;
  const float4* p = (const float4*)(in + (size_t)t * 8);
  float4 v0 = p[0], v1 = p[1];
  uint4 w;
  w.x = (unsigned)f2bf(v0.x) | ((unsigned)f2bf(v0.y) << 16);
  w.y = (unsigned)f2bf(v0.z) | ((unsigned)f2bf(v0.w) << 16);
  w.z = (unsigned)f2bf(v1.x) | ((unsigned)f2bf(v1.y) << 16);
  w.w = (unsigned)f2bf(v1.z) | ((unsigned)f2bf(v1.w) << 16);
  *(uint4*)(out + (size_t)t * 8) = w;
}

// ---------------------------------------------------------------------------
// Gather embedding rows into bf16 A matrix [16384][1024]
__global__ __launch_bounds__(256) void gather_emb(const int* __restrict__ x,
    const float* __restrict__ arg_emb, ushort* __restrict__ Ag)
{
  int t = blockIdx.x * 256 + threadIdx.x;
  size_t base = (size_t)t * 8;
  int m = (int)(base >> 10), kk = (int)(base & 1023);
  int j = kk >> 7, c = kk & 127;
  int b = m >> 9, s = m & 511;
  int a = x[(size_t)(s * B_ + b) * 9 + 1 + j];
  const float4* p = (const float4*)(arg_emb + (size_t)a * 128 + c);
  float4 v0 = p[0], v1 = p[1];
  uint4 w;
  w.x = (unsigned)f2bf(v0.x) | ((unsigned)f2bf(v0.y) << 16);
  w.y = (unsigned)f2bf(v0.z) | ((unsigned)f2bf(v0.w) << 16);
  w.z = (unsigned)f2bf(v1.x) | ((unsigned)f2bf(v1.y) << 16);
  w.w = (unsigned)f2bf(v1.z) | ((unsigned)f2bf(v1.w) << 16);
  *(uint4*)(Ag + base) = w;
}

// ---------------------------------------------------------------------------
// bf16 MFMA GEMM: C[M,N] = epi(A[M,K] @ W[N,K]^T + bias)
// EPI: 0 = f32 store, 1 = relu -> bf16 store, 2 = f32 residual add
template<int EPI>
__global__ __launch_bounds__(256) void gemm_mfma(
    const ushort* __restrict__ A, const ushort* __restrict__ W,
    const float* __restrict__ bias, void* __restrict__ Cout,
    int M, int N, int K)
{
  __shared__ ushort As[128 * 64];
  __shared__ ushort Bs[128 * 64];
  const int tid = threadIdx.x;
  const int lane = tid & 63, wv = tid >> 6;
  const int wr = wv >> 1, wc = wv & 1;
  const int row0 = blockIdx.y << 7, col0 = blockIdx.x << 7;

  f32x4 acc[4][4] = {};

  for (int k0 = 0; k0 < K; k0 += 64) {
    #pragma unroll
    for (int i = 0; i < 4; i++) {
      int c = i * 256 + wv * 64 + lane;
      int r = c >> 3, c8 = (c & 7) << 3;
      gload16(A + (size_t)(row0 + r) * K + k0 + c8, As + c * 8);
      gload16(W + (size_t)(col0 + r) * K + k0 + c8, Bs + c * 8);
    }
    __syncthreads();
    #pragma unroll
    for (int kk = 0; kk < 2; kk++) {
      const int kb = kk * 32 + ((lane >> 4) << 3);
      bf16x8 af[4], bfr[4];
      #pragma unroll
      for (int m = 0; m < 4; m++)
        af[m] = *(const bf16x8*)(As + (wr * 64 + m * 16 + (lane & 15)) * 64 + kb);
      #pragma unroll
      for (int n = 0; n < 4; n++)
        bfr[n] = *(const bf16x8*)(Bs + (wc * 64 + n * 16 + (lane & 15)) * 64 + kb);
      #pragma unroll
      for (int m = 0; m < 4; m++)
        #pragma unroll
        for (int n = 0; n < 4; n++)
          acc[m][n] = __builtin_amdgcn_mfma_f32_16x16x32_bf16(af[m], bfr[n], acc[m][n], 0, 0, 0);
    }
    __syncthreads();
  }

  const int crow = row0 + wr * 64 + ((lane >> 4) << 2);
  const int ccol = col0 + wc * 64 + (lane & 15);
  #pragma unroll
  for (int n = 0; n < 4; n++) {
    int col = ccol + n * 16;
    float bv = bias[col];
    #pragma unroll
    for (int m = 0; m < 4; m++) {
      int rowb = crow + m * 16;
      #pragma unroll
      for (int j = 0; j < 4; j++) {
        float val = acc[m][n][j] + bv;
        size_t off = (size_t)(rowb + j) * N + col;
        if (EPI == 0) ((float*)Cout)[off] = val;
        if (EPI == 1) ((ushort*)Cout)[off] = f2bf(fmaxf(val, 0.f));
        if (EPI == 2) ((float*)Cout)[off] += val;
      }
    }
  }
}

// ---------------------------------------------------------------------------
// LayerNorm: one wave per row, bf16 output.
__global__ __launch_bounds__(256) void ln_bf(const float* __restrict__ in,
    ushort* __restrict__ out, const float* __restrict__ g, const float* __restrict__ b)
{
  int row  = (blockIdx.x << 2) + (threadIdx.x >> 6);
  int lane = threadIdx.x & 63;
  const float* r = in + (size_t)row * D_;
  float4 v0 = *(const float4*)(r + lane * 4);
  float4 v1 = *(const float4*)(r + 256 + lane * 4);
  float s = v0.x + v0.y + v0.z + v0.w + v1.x + v1.y + v1.z + v1.w;
  #pragma unroll
  for (int m = 1; m < 64; m <<= 1) s += __shfl_xor(s, m);
  float mean = s * (1.0f / 512.0f);
  float a0 = v0.x - mean, a1 = v0.y - mean, a2 = v0.z - mean, a3 = v0.w - mean;
  float a4 = v1.x - mean, a5 = v1.y - mean, a6 = v1.z - mean, a7 = v1.w - mean;
  float sq = a0*a0 + a1*a1 + a2*a2 + a3*a3 + a4*a4 + a5*a5 + a6*a6 + a7*a7;
  #pragma unroll
  for (int m = 1; m < 64; m <<= 1) sq += __shfl_xor(sq, m);
  float inv = rsqrtf(sq * (1.0f / 512.0f) + 1e-5f);
  float4 g0 = *(const float4*)(g + lane * 4);
  float4 g1 = *(const float4*)(g + 256 + lane * 4);
  float4 b0 = *(const float4*)(b + lane * 4);
  float4 b1 = *(const float4*)(b + 256 + lane * 4);
  ushort* o = out + (size_t)row * D_;
  ushort4 u0, u1;
  u0.x = f2bf(a0*inv*g0.x + b0.x); u0.y = f2bf(a1*inv*g0.y + b0.y);
  u0.z = f2bf(a2*inv*g0.z + b0.z); u0.w = f2bf(a3*inv*g0.w + b0.w);
  u1.x = f2bf(a4*inv*g1.x + b1.x); u1.y = f2bf(a5*inv*g1.y + b1.y);
  u1.z = f2bf(a6*inv*g1.z + b1.z); u1.w = f2bf(a7*inv*g1.w + b1.w);
  *(ushort4*)(o + lane * 4) = u0;
  *(ushort4*)(o + 256 + lane * 4) = u1;
}

// ---------------------------------------------------------------------------
// Flash attention, 64x64 tiles, f32.  MODE 0: flash only. MODE 1: pass1 (m,l)
// + pass2 (write normalized p to global, accumulate O).
template<int MODE>
__global__ __launch_bounds__(256) void attn_flash(
    const float* __restrict__ qg, const float* __restrict__ kg,
    const float* __restrict__ vg, ushort* __restrict__ og,
    float* __restrict__ pout)
{
  __shared__ float Qs[64][68];
  __shared__ float Ks[64][68];
  __shared__ float Vs[64][68];
  __shared__ float Ps[64][68];
  const int qt = blockIdx.x, hh = blockIdx.y, b = blockIdx.z;
  const int tid = threadIdx.x;
  const int tx = tid & 15, ty = tid >> 4;
  const size_t bbase = (size_t)b * S_ * D_ + hh * 64;

  #pragma unroll
  for (int i = 0; i < 4; i++) {
    int c = i * 256 + tid, r = c >> 4, c4 = (c & 15) << 2;
    *(float4*)&Qs[r][c4] = *(const float4*)(qg + bbase + (size_t)(qt * 64 + r) * D_ + c4);
  }

  float mrow[4], lrow[4];
  float oacc[4][4] = {};
  #pragma unroll
  for (int i = 0; i < 4; i++) { mrow[i] = -3e38f; lrow[i] = 0.f; }

  for (int kt = 0; kt <= qt; kt++) {
    __syncthreads();
    #pragma unroll
    for (int i = 0; i < 4; i++) {
      int c = i * 256 + tid, r = c >> 4, c4 = (c & 15) << 2;
      *(float4*)&Ks[r][c4] = *(const float4*)(kg + bbase + (size_t)(kt * 64 + r) * D_ + c4);
      if (MODE == 0)
        *(float4*)&Vs[r][c4] = *(const float4*)(vg + bbase + (size_t)(kt * 64 + r) * D_ + c4);
    }
    __syncthreads();

    float s[4][4] = {};
    #pragma unroll
    for (int k4 = 0; k4 < 16; k4++) {
      float4 aq[4], bk[4];
      #pragma unroll
      for (int r2 = 0; r2 < 4; r2++) aq[r2] = *(const float4*)&Qs[ty * 4 + r2][k4 * 4];
      #pragma unroll
      for (int r2 = 0; r2 < 4; r2++) bk[r2] = *(const float4*)&Ks[tx * 4 + r2][k4 * 4];
      #pragma unroll
      for (int i2 = 0; i2 < 4; i2++)
        #pragma unroll
        for (int j = 0; j < 4; j++)
          s[i2][j] += aq[i2].x*bk[j].x + aq[i2].y*bk[j].y + aq[i2].z*bk[j].z + aq[i2].w*bk[j].w;
    }
    const bool diag = (kt == qt);
    #pragma unroll
    for (int i2 = 0; i2 < 4; i2++) {
      int qr = ty * 4 + i2;
      #pragma unroll
      for (int j = 0; j < 4; j++) {
        float sv = s[i2][j] * 0.125f;
        if (diag && (tx * 4 + j > qr)) sv = -3e38f;
        s[i2][j] = sv;
      }
    }
    #pragma unroll
    for (int i2 = 0; i2 < 4; i2++) {
      float rm = fmaxf(fmaxf(s[i2][0], s[i2][1]), fmaxf(s[i2][2], s[i2][3]));
      #pragma unroll
      for (int mm = 1; mm < 16; mm <<= 1) rm = fmaxf(rm, __shfl_xor(rm, mm));
      float nm = fmaxf(mrow[i2], rm);
      float fac = __expf(mrow[i2] - nm);
      mrow[i2] = nm;
      float psum = 0.f;
      #pragma unroll
      for (int j = 0; j < 4; j++) {
        float p = __expf(s[i2][j] - nm);
        psum += p;
        if (MODE == 0) Ps[ty * 4 + i2][tx * 4 + j] = p;
      }
      #pragma unroll
      for (int mm = 1; mm < 16; mm <<= 1) psum += __shfl_xor(psum, mm);
      lrow[i2] = lrow[i2] * fac + psum;
      if (MODE == 0) {
        #pragma unroll
        for (int j = 0; j < 4; j++) oacc[i2][j] *= fac;
      }
    }
    if (MODE == 0) {
      // Ps rows are wave-local (rows 16w..16w+15): in-order DS pipe, no barrier.
      #pragma unroll
      for (int k4 = 0; k4 < 16; k4++) {
        float4 pa[4], vv[4];
        #pragma unroll
        for (int r2 = 0; r2 < 4; r2++) pa[r2] = *(const float4*)&Ps[ty * 4 + r2][k4 * 4];
        #pragma unroll
        for (int kl = 0; kl < 4; kl++) vv[kl] = *(const float4*)&Vs[k4 * 4 + kl][tx * 4];
        #pragma unroll
        for (int i2 = 0; i2 < 4; i2++) {
          float4 p = pa[i2];
          oacc[i2][0] += p.x*vv[0].x + p.y*vv[1].x + p.z*vv[2].x + p.w*vv[3].x;
          oacc[i2][1] += p.x*vv[0].y + p.y*vv[1].y + p.z*vv[2].y + p.w*vv[3].y;
          oacc[i2][2] += p.x*vv[0].z + p.y*vv[1].z + p.z*vv[2].z + p.w*vv[3].z;
          oacc[i2][3] += p.x*vv[0].w + p.y*vv[1].w + p.z*vv[2].w + p.w*vv[3].w;
        }
      }
    }
  }

  if (MODE == 1) {
    float invl[4];
    #pragma unroll
    for (int i2 = 0; i2 < 4; i2++) invl[i2] = 1.0f / lrow[i2];
    for (int kt = 0; kt < 8; kt++) {
      float pw[4][4];
      if (kt <= qt) {
        __syncthreads();
        #pragma unroll
        for (int i = 0; i < 4; i++) {
          int c = i * 256 + tid, r = c >> 4, c4 = (c & 15) << 2;
          *(float4*)&Ks[r][c4] = *(const float4*)(kg + bbase + (size_t)(kt * 64 + r) * D_ + c4);
          *(float4*)&Vs[r][c4] = *(const float4*)(vg + bbase + (size_t)(kt * 64 + r) * D_ + c4);
        }
        __syncthreads();
        float s[4][4] = {};
        #pragma unroll
        for (int k4 = 0; k4 < 16; k4++) {
          float4 aq[4], bk[4];
          #pragma unroll
          for (int r2 = 0; r2 < 4; r2++) aq[r2] = *(const float4*)&Qs[ty * 4 + r2][k4 * 4];
          #pragma unroll
          for (int r2 = 0; r2 < 4; r2++) bk[r2] = *(const float4*)&Ks[tx * 4 + r2][k4 * 4];
          #pragma unroll
          for (int i2 = 0; i2 < 4; i2++)
            #pragma unroll
            for (int j = 0; j < 4; j++)
              s[i2][j] += aq[i2].x*bk[j].x + aq[i2].y*bk[j].y + aq[i2].z*bk[j].z + aq[i2].w*bk[j].w;
        }
        const bool diag = (kt == qt);
        #pragma unroll
        for (int i2 = 0; i2 < 4; i2++) {
          int qr = ty * 4 + i2;
          #pragma unroll
          for (int j = 0; j < 4; j++) {
            float sv = s[i2][j] * 0.125f;
            if (diag && (tx * 4 + j > qr)) sv = -3e38f;
            float p = __expf(sv - mrow[i2]) * invl[i2];
            pw[i2][j] = p;
            Ps[ty * 4 + i2][tx * 4 + j] = p;
          }
        }
        #pragma unroll
        for (int k4 = 0; k4 < 16; k4++) {
          float4 pa[4], vv[4];
          #pragma unroll
          for (int r2 = 0; r2 < 4; r2++) pa[r2] = *(const float4*)&Ps[ty * 4 + r2][k4 * 4];
          #pragma unroll
          for (int kl = 0; kl < 4; kl++) vv[kl] = *(const float4*)&Vs[k4 * 4 + kl][tx * 4];
          #pragma unroll
          for (int i2 = 0; i2 < 4; i2++) {
            float4 p = pa[i2];
            oacc[i2][0] += p.x*vv[0].x + p.y*vv[1].x + p.z*vv[2].x + p.w*vv[3].x;
            oacc[i2][1] += p.x*vv[0].y + p.y*vv[1].y + p.z*vv[2].y + p.w*vv[3].y;
            oacc[i2][2] += p.x*vv[0].z + p.y*vv[1].z + p.z*vv[2].z + p.w*vv[3].z;
            oacc[i2][3] += p.x*vv[0].w + p.y*vv[1].w + p.z*vv[2].w + p.w*vv[3].w;
          }
        }
      } else {
        #pragma unroll
        for (int i2 = 0; i2 < 4; i2++)
          #pragma unroll
          for (int j = 0; j < 4; j++) pw[i2][j] = 0.f;
      }
      #pragma unroll
      for (int i2 = 0; i2 < 4; i2++) {
        int qq = qt * 64 + ty * 4 + i2;
        float4 w4 = make_float4(pw[i2][0], pw[i2][1], pw[i2][2], pw[i2][3]);
        *(float4*)(pout + ((size_t)((b * H_ + hh) * S_ + qq)) * S_ + kt * 64 + tx * 4) = w4;
      }
    }
  }

  // write O (bf16)
  #pragma unroll
  for (int i2 = 0; i2 < 4; i2++) {
    float inv = (MODE == 0) ? 1.0f / lrow[i2] : 1.0f;
    int gq = qt * 64 + ty * 4 + i2;
    ushort4 u;
    u.x = f2bf(oacc[i2][0] * inv); u.y = f2bf(oacc[i2][1] * inv);
    u.z = f2bf(oacc[i2][2] * inv); u.w = f2bf(oacc[i2][3] * inv);
    *(ushort4*)(og + (size_t)(b * S_ + gq) * D_ + hh * 64 + tx * 4) = u;
  }
}

// ---------------------------------------------------------------------------
// Finish embedding: h += cmd_emb[cmd] + pos_enc(s);  row s==0 := cls_emb[trg_char[b]]
__global__ __launch_bounds__(128) void embed_finish(float* __restrict__ h,
    const int* __restrict__ x, const float* __restrict__ cmd_emb,
    const float* __restrict__ cls_emb, const int* __restrict__ trg_char)
{
  int m = blockIdx.x, b = m >> 9, s = m & 511;
  int d = threadIdx.x << 2;
  float4* hp = (float4*)(h + (size_t)m * D_ + d);
  if (s == 0) {
    int c = trg_char[b];
    *hp = *(const float4*)(cls_emb + (size_t)c * D_ + d);
  } else {
    int cmd = x[(size_t)(s * B_ + b) * 9];
    float4 v  = *hp;
    float4 ce = *(const float4*)(cmd_emb + (size_t)cmd * D_ + d);
    const float kfac = -0.017988946039f;   // -ln(10000)/512
    int i0 = d >> 1;
    float ang0 = (float)s * expf((float)(2 * i0) * kfac);
    float ang1 = (float)s * expf((float)(2 * (i0 + 1)) * kfac);
    v.x += ce.x + sinf(ang0);
    v.y += ce.y + cosf(ang0);
    v.z += ce.z + sinf(ang1);
    v.w += ce.w + cosf(ang1);
    *hp = v;
  }
}

// ---------------------------------------------------------------------------
// Cross-attention precompute (softmax over single key == 1)
__global__ __launch_bounds__(256) void ca_stage(const float* __restrict__ in,
    const float* __restrict__ ca_w, const float* __restrict__ ca_b,
    float* __restrict__ outb, int wsel, int in_is_per_l)
{
  int l = blockIdx.x >> 5, b = blockIdx.x & 31;
  __shared__ float sm[512];
  const float* src = in_is_per_l ? in + ((size_t)l * 32 + b) * 512 : in + (size_t)b * 512;
  for (int i = threadIdx.x; i < 512; i += 256) sm[i] = src[i];
  __syncthreads();
  const float* Wl = ca_w + ((size_t)(l * 4 + wsel)) * 512 * 512;
  const float* bl = ca_b + (l * 4 + wsel) * 512;
  for (int n = threadIdx.x; n < 512; n += 256) {
    const float* wr = Wl + (size_t)n * 512;
    float acc = 0.f;
    for (int k2 = 0; k2 < 512; k2 += 4) {
      float4 w4 = *(const float4*)(wr + k2);
      acc += sm[k2] * w4.x + sm[k2+1] * w4.y + sm[k2+2] * w4.z + sm[k2+3] * w4.w;
    }
    outb[((size_t)l * 32 + b) * 512 + n] = acc + bl[n];
  }
}

__global__ __launch_bounds__(128) void add_ca(float* __restrict__ h,
    const float* __restrict__ ca)
{
  int m = blockIdx.x, b = m >> 9;
  int d = threadIdx.x << 2;
  float4* hp = (float4*)(h + (size_t)m * D_ + d);
  float4 v = *hp;
  float4 c = *(const float4*)(ca + (size_t)b * D_ + d);
  v.x += c.x; v.y += c.y; v.z += c.z; v.w += c.w;
  *hp = v;
}

// cmd head: bf16 xn input
__global__ __launch_bounds__(256) void cmd_head(const ushort* __restrict__ xn,
    const float* __restrict__ cw, const float* __restrict__ cb, float* __restrict__ out)
{
  int row  = (blockIdx.x << 2) + (threadIdx.x >> 6);
  int lane = threadIdx.x & 63;
  uint4 raw = *(const uint4*)(xn + (size_t)row * D_ + lane * 8);
  float x0 = bf2f(raw.x & 0xffff), x1 = bf2f(raw.x >> 16);
  float x2 = bf2f(raw.y & 0xffff), x3 = bf2f(raw.y >> 16);
  float x4 = bf2f(raw.z & 0xffff), x5 = bf2f(raw.z >> 16);
  float x6 = bf2f(raw.w & 0xffff), x7 = bf2f(raw.w >> 16);
  #pragma unroll
  for (int n = 0; n < 4; n++) {
    const float* w = cw + n * 512 + lane * 8;
    float4 w0 = *(const float4*)w, w1 = *(const float4*)(w + 4);
    float p = x0*w0.x + x1*w0.y + x2*w0.z + x3*w0.w
            + x4*w1.x + x5*w1.y + x6*w1.z + x7*w1.w;
    #pragma unroll
    for (int m = 1; m < 64; m <<= 1) p += __shfl_xor(p, m);
    if (lane == 0) out[(size_t)row * 4 + n] = p + cb[n];
  }
}

// ---------------------------------------------------------------------------
extern "C" void kernel_launch(void* const* d_in, const int* in_sizes, int n_in,
                              void* d_out, int out_size, void* d_ws, size_t ws_size,
                              hipStream_t stream)
{
  const int*   x          = (const int*)  d_in[0];
  const float* memory     = (const float*)d_in[1];
  const int*   trg_char   = (const int*)  d_in[2];
  const float* cmd_emb    = (const float*)d_in[4];
  const float* arg_emb    = (const float*)d_in[5];
  const float* embed_w    = (const float*)d_in[6];
  const float* embed_b    = (const float*)d_in[7];
  const float* sa_w       = (const float*)d_in[8];
  const float* sa_b       = (const float*)d_in[9];
  const float* ca_w       = (const float*)d_in[10];
  const float* ca_b       = (const float*)d_in[11];
  const float* ff_w1      = (const float*)d_in[12];
  const float* ff_b1      = (const float*)d_in[13];
  const float* ff_w2      = (const float*)d_in[14];
  const float* ff_b2      = (const float*)d_in[15];
  const float* ln_g       = (const float*)d_in[16];
  const float* ln_b       = (const float*)d_in[17];
  const float* fn_g       = (const float*)d_in[18];
  const float* fn_b       = (const float*)d_in[19];
  const float* cls_emb    = (const float*)d_in[20];
  const float* cmd_w      = (const float*)d_in[21];
  const float* cmd_b      = (const float*)d_in[22];
  const float* argf_w     = (const float*)d_in[23];
  const float* argf_b     = (const float*)d_in[24];

  float* out_cmd  = (float*)d_out;
  float* out_args = out_cmd + (size_t)M_ * 4;
  float* out_attn = out_args + (size_t)M_ * 1024;

  const size_t MS = (size_t)M_ * D_;     // 8388608
  float* ws    = (float*)d_ws;
  float* h     = ws;
  float* qb    = ws + MS;
  float* kb    = ws + 2 * MS;
  float* vb    = ws + 3 * MS;
  float* tA    = ws + 4 * MS;            // FF intermediate bf16 / embed gather bf16
  ushort* tA_bf = (ushort*)tA;
  ushort* xn_bf = (ushort*)(ws + 5 * MS);
  ushort* o_bf  = (ushort*)((char*)(ws + 5 * MS) + MS * 2);
  ushort* wbf   = (ushort*)(ws + 6 * MS);
  ushort* sa_wb   = wbf;                         // 6291456
  ushort* ff1_wb  = wbf + 6291456;               // 3145728
  ushort* ff2_wb  = wbf + 9437184;               // 3145728
  ushort* emb_wb  = wbf + 12582912;              // 524288
  ushort* argf_wb = wbf + 13107200;              // 524288
  float* vvec   = ws + 6 * MS + 6815744;
  float* ca_out = vvec + 6 * 32 * 512;

  dim3 blk256(256), blk128(128);
  dim3 g_g512(4, 128);      // N=512 tiles
  dim3 g_g1024(8, 128);     // N=1024 tiles
  dim3 g_ln(M_ / 4);
  dim3 g_attn(8, H_, B_);
  dim3 g_row(M_);

  // Weight conversion to bf16
  cvt_bf16<<<dim3(3072), blk256, 0, stream>>>(sa_w,   sa_wb,   786432);
  cvt_bf16<<<dim3(1536), blk256, 0, stream>>>(ff_w1,  ff1_wb,  393216);
  cvt_bf16<<<dim3(1536), blk256, 0, stream>>>(ff_w2,  ff2_wb,  393216);
  cvt_bf16<<<dim3(256),  blk256, 0, stream>>>(embed_w, emb_wb,  65536);
  cvt_bf16<<<dim3(256),  blk256, 0, stream>>>(argf_w, argf_wb,  65536);

  // Cross-attention precompute
  ca_stage<<<dim3(L_ * 32), blk256, 0, stream>>>(memory, ca_w, ca_b, vvec, 2, 0);
  ca_stage<<<dim3(L_ * 32), blk256, 0, stream>>>(vvec, ca_w, ca_b, ca_out, 3, 1);

  // Embedding
  gather_emb<<<dim3(8192), blk256, 0, stream>>>(x, arg_emb, tA_bf);
  gemm_mfma<0><<<g_g512, blk256, 0, stream>>>(tA_bf, emb_wb, embed_b, h, M_, D_, 1024);
  embed_finish<<<g_row, blk128, 0, stream>>>(h, x, cmd_emb, cls_emb, trg_char);

  for (int l = 0; l < L_; l++) {
    const ushort* saW = sa_wb + (size_t)l * 4 * D_ * D_;
    const float*  saB = sa_b + (size_t)l * 4 * D_;
    ln_bf<<<g_ln, blk256, 0, stream>>>(h, xn_bf, ln_g + (l * 3 + 0) * D_, ln_b + (l * 3 + 0) * D_);
    gemm_mfma<0><<<g_g512, blk256, 0, stream>>>(xn_bf, saW,                    saB,          qb, M_, D_, D_);
    gemm_mfma<0><<<g_g512, blk256, 0, stream>>>(xn_bf, saW + (size_t)D_*D_,    saB + D_,     kb, M_, D_, D_);
    gemm_mfma<0><<<g_g512, blk256, 0, stream>>>(xn_bf, saW + (size_t)2*D_*D_,  saB + 2*D_,   vb, M_, D_, D_);
    if (l == L_ - 1)
      attn_flash<1><<<g_attn, blk256, 0, stream>>>(qb, kb, vb, o_bf, out_attn);
    else
      attn_flash<0><<<g_attn, blk256, 0, stream>>>(qb, kb, vb, o_bf, nullptr);
    gemm_mfma<2><<<g_g512, blk256, 0, stream>>>(o_bf, saW + (size_t)3*D_*D_, saB + 3*D_, h, M_, D_, D_);
    add_ca<<<g_row, blk128, 0, stream>>>(h, ca_out + (size_t)l * 32 * D_);
    ln_bf<<<g_ln, blk256, 0, stream>>>(h, xn_bf, ln_g + (l * 3 + 2) * D_, ln_b + (l * 3 + 2) * D_);
    gemm_mfma<1><<<g_g1024, blk256, 0, stream>>>(xn_bf, ff1_wb + (size_t)l*DFF_*D_, ff_b1 + l*DFF_, tA_bf, M_, DFF_, D_);
    gemm_mfma<2><<<g_g512,  blk256, 0, stream>>>(tA_bf, ff2_wb + (size_t)l*D_*DFF_, ff_b2 + l*D_,   h,     M_, D_, DFF_);
  }

  ln_bf<<<g_ln, blk256, 0, stream>>>(h, xn_bf, fn_g, fn_b);
  gemm_mfma<0><<<g_g1024, blk256, 0, stream>>>(xn_bf, argf_wb, argf_b, out_args, M_, 1024, D_);
  cmd_head<<<dim3(M_ / 4), blk256, 0, stream>>>(xn_bf, cmd_w, cmd_b, out_cmd);
}

// Round 3
// 1810.118 us; speedup vs baseline: 15.1051x; 3.0267x over previous
//
#include <hip/hip_runtime.h>
#include <hip/hip_bf16.h>

#define S_ 512
#define B_ 32
#define D_ 512
#define H_ 8
#define L_ 6
#define DFF_ 1024
#define M_ (B_*S_)   // 16384 rows

typedef __attribute__((ext_vector_type(8))) short bf16x8;
typedef __attribute__((ext_vector_type(4))) float f32x4;

__device__ __forceinline__ ushort f2bf(float f) {
  union { float f; unsigned int u; } x; x.f = f;
  unsigned int r = x.u + 0x7fffu + ((x.u >> 16) & 1u);
  return (ushort)(r >> 16);
}
__device__ __forceinline__ float bf2f(unsigned int u) {
  union { unsigned int u; float f; } x; x.u = u << 16;
  return x.f;
}

__device__ __forceinline__ void gload16(const ushort* g, ushort* l) {
  __builtin_amdgcn_global_load_lds(
      (const __attribute__((address_space(1))) unsigned int*)g,
      (__attribute__((address_space(3))) unsigned int*)l, 16, 0, 0);
}

// ---------------------------------------------------------------------------
// f32 -> bf16 bulk convert
__global__ __launch_bounds__(256) void cvt_bf16(const float* __restrict__ in,
    ushort* __restrict__ out, int n8)
{
  int t = blockIdx.x * 256 + threadIdx.x;
  if (t >= n8) return;
  const float4* p = (const float4*)(in + (size_t)t * 8);
  float4 v0 = p[0], v1 = p[1];
  uint4 w;
  w.x = (unsigned)f2bf(v0.x) | ((unsigned)f2bf(v0.y) << 16);
  w.y = (unsigned)f2bf(v0.z) | ((unsigned)f2bf(v0.w) << 16);
  w.z = (unsigned)f2bf(v1.x) | ((unsigned)f2bf(v1.y) << 16);
  w.w = (unsigned)f2bf(v1.z) | ((unsigned)f2bf(v1.w) << 16);
  *(uint4*)(out + (size_t)t * 8) = w;
}

// ---------------------------------------------------------------------------
// Gather embedding rows into bf16 A matrix [16384][1024]
__global__ __launch_bounds__(256) void gather_emb(const int* __restrict__ x,
    const float* __restrict__ arg_emb, ushort* __restrict__ Ag)
{
  int t = blockIdx.x * 256 + threadIdx.x;
  size_t base = (size_t)t * 8;
  int m = (int)(base >> 10), kk = (int)(base & 1023);
  int j = kk >> 7, c = kk & 127;
  int b = m >> 9, s = m & 511;
  int a = x[(size_t)(s * B_ + b) * 9 + 1 + j];
  const float4* p = (const float4*)(arg_emb + (size_t)a * 128 + c);
  float4 v0 = p[0], v1 = p[1];
  uint4 w;
  w.x = (unsigned)f2bf(v0.x) | ((unsigned)f2bf(v0.y) << 16);
  w.y = (unsigned)f2bf(v0.z) | ((unsigned)f2bf(v0.w) << 16);
  w.z = (unsigned)f2bf(v1.x) | ((unsigned)f2bf(v1.y) << 16);
  w.w = (unsigned)f2bf(v1.z) | ((unsigned)f2bf(v1.w) << 16);
  *(uint4*)(Ag + base) = w;
}

// ---------------------------------------------------------------------------
// bf16 MFMA GEMM: C[M,N] = epi(A[M,K] @ W[N,K]^T + bias)
// EPI: 0 = f32 store, 1 = relu -> bf16 store, 2 = f32 residual add, 3 = bf16 store
template<int EPI>
__global__ __launch_bounds__(256) void gemm_mfma(
    const ushort* __restrict__ A, const ushort* __restrict__ W,
    const float* __restrict__ bias, void* __restrict__ Cout,
    int M, int N, int K)
{
  __shared__ ushort As[128 * 64];
  __shared__ ushort Bs[128 * 64];
  const int tid = threadIdx.x;
  const int lane = tid & 63, wv = tid >> 6;
  const int wr = wv >> 1, wc = wv & 1;
  const int row0 = blockIdx.y << 7, col0 = blockIdx.x << 7;

  f32x4 acc[4][4] = {};

  for (int k0 = 0; k0 < K; k0 += 64) {
    #pragma unroll
    for (int i = 0; i < 4; i++) {
      int c = i * 256 + wv * 64 + lane;
      int r = c >> 3, c8 = (c & 7) << 3;
      gload16(A + (size_t)(row0 + r) * K + k0 + c8, As + c * 8);
      gload16(W + (size_t)(col0 + r) * K + k0 + c8, Bs + c * 8);
    }
    __syncthreads();
    #pragma unroll
    for (int kk = 0; kk < 2; kk++) {
      const int kb = kk * 32 + ((lane >> 4) << 3);
      bf16x8 af[4], bfr[4];
      #pragma unroll
      for (int m = 0; m < 4; m++)
        af[m] = *(const bf16x8*)(As + (wr * 64 + m * 16 + (lane & 15)) * 64 + kb);
      #pragma unroll
      for (int n = 0; n < 4; n++)
        bfr[n] = *(const bf16x8*)(Bs + (wc * 64 + n * 16 + (lane & 15)) * 64 + kb);
      #pragma unroll
      for (int m = 0; m < 4; m++)
        #pragma unroll
        for (int n = 0; n < 4; n++)
          acc[m][n] = __builtin_amdgcn_mfma_f32_16x16x32_bf16(af[m], bfr[n], acc[m][n], 0, 0, 0);
    }
    __syncthreads();
  }

  const int crow = row0 + wr * 64 + ((lane >> 4) << 2);
  const int ccol = col0 + wc * 64 + (lane & 15);
  #pragma unroll
  for (int n = 0; n < 4; n++) {
    int col = ccol + n * 16;
    float bv = bias[col];
    #pragma unroll
    for (int m = 0; m < 4; m++) {
      int rowb = crow + m * 16;
      #pragma unroll
      for (int j = 0; j < 4; j++) {
        float val = acc[m][n][j] + bv;
        size_t off = (size_t)(rowb + j) * N + col;
        if (EPI == 0) ((float*)Cout)[off] = val;
        if (EPI == 1) ((ushort*)Cout)[off] = f2bf(fmaxf(val, 0.f));
        if (EPI == 2) ((float*)Cout)[off] += val;
        if (EPI == 3) ((ushort*)Cout)[off] = f2bf(val);
      }
    }
  }
}

// ---------------------------------------------------------------------------
// LayerNorm: one wave per row, bf16 output.
__global__ __launch_bounds__(256) void ln_bf(const float* __restrict__ in,
    ushort* __restrict__ out, const float* __restrict__ g, const float* __restrict__ b)
{
  int row  = (blockIdx.x << 2) + (threadIdx.x >> 6);
  int lane = threadIdx.x & 63;
  const float* r = in + (size_t)row * D_;
  float4 v0 = *(const float4*)(r + lane * 4);
  float4 v1 = *(const float4*)(r + 256 + lane * 4);
  float s = v0.x + v0.y + v0.z + v0.w + v1.x + v1.y + v1.z + v1.w;
  #pragma unroll
  for (int m = 1; m < 64; m <<= 1) s += __shfl_xor(s, m);
  float mean = s * (1.0f / 512.0f);
  float a0 = v0.x - mean, a1 = v0.y - mean, a2 = v0.z - mean, a3 = v0.w - mean;
  float a4 = v1.x - mean, a5 = v1.y - mean, a6 = v1.z - mean, a7 = v1.w - mean;
  float sq = a0*a0 + a1*a1 + a2*a2 + a3*a3 + a4*a4 + a5*a5 + a6*a6 + a7*a7;
  #pragma unroll
  for (int m = 1; m < 64; m <<= 1) sq += __shfl_xor(sq, m);
  float inv = rsqrtf(sq * (1.0f / 512.0f) + 1e-5f);
  float4 g0 = *(const float4*)(g + lane * 4);
  float4 g1 = *(const float4*)(g + 256 + lane * 4);
  float4 b0 = *(const float4*)(b + lane * 4);
  float4 b1 = *(const float4*)(b + 256 + lane * 4);
  ushort* o = out + (size_t)row * D_;
  ushort4 u0, u1;
  u0.x = f2bf(a0*inv*g0.x + b0.x); u0.y = f2bf(a1*inv*g0.y + b0.y);
  u0.z = f2bf(a2*inv*g0.z + b0.z); u0.w = f2bf(a3*inv*g0.w + b0.w);
  u1.x = f2bf(a4*inv*g1.x + b1.x); u1.y = f2bf(a5*inv*g1.y + b1.y);
  u1.z = f2bf(a6*inv*g1.z + b1.z); u1.w = f2bf(a7*inv*g1.w + b1.w);
  *(ushort4*)(o + lane * 4) = u0;
  *(ushort4*)(o + 256 + lane * 4) = u1;
}

// ---------------------------------------------------------------------------
// MFMA flash attention. qkv: bf16 [M][1536] (q|k|v). og: bf16 [M][512].
// 64q x 64k tiles; 4 waves, each owns 16 q-rows. MODE 1: two-pass, writes
// normalized p (f32) to pout, zeros above diagonal.
// Fragment layouts (validated by gemm_mfma): A row=lane&15, k=kk*32+(lane>>4)*8+j;
// C col=lane&15 (+16n), row=(lane>>4)*4+j.
#define QS_ 88   // Q/K LDS stride (bf16)
#define PS_ 72   // P / Vt LDS stride (bf16)
template<int MODE>
__global__ __launch_bounds__(256) void attn_mfma(const ushort* __restrict__ qkv,
    ushort* __restrict__ og, float* __restrict__ pout)
{
  __shared__ ushort Qs[64 * QS_];
  __shared__ ushort Ks[64 * QS_];
  __shared__ ushort Vt[64 * PS_];   // [d][key]
  __shared__ ushort Ps[64 * PS_];   // [q][key], per-wave 16-row regions
  const int qt = 7 - blockIdx.x;    // heavy tiles first
  const int h = blockIdx.y, b = blockIdx.z;
  const int tid = threadIdx.x;
  const int w = tid >> 6, lane = tid & 63;
  const int l = lane & 15, g = lane >> 4;
  const size_t qbase = ((size_t)b * S_) * 1536 + h * 64;

  // stage Q (once)
  #pragma unroll
  for (int p = 0; p < 2; p++) {
    int c = p * 256 + tid; int r = c >> 3, col = (c & 7) * 8;
    *(bf16x8*)&Qs[r * QS_ + col] =
        *(const bf16x8*)(qkv + qbase + (size_t)(qt * 64 + r) * 1536 + col);
  }

  float mrow[4] = {-3e38f, -3e38f, -3e38f, -3e38f};
  float lrow[4] = {0.f, 0.f, 0.f, 0.f};
  f32x4 oacc[4] = {};

  if (MODE == 1) {
    // pass 1: m,l only (K staging only)
    for (int kt = 0; kt <= qt; kt++) {
      __syncthreads();
      #pragma unroll
      for (int p = 0; p < 2; p++) {
        int c = p * 256 + tid; int r = c >> 3, col = (c & 7) * 8;
        *(bf16x8*)&Ks[r * QS_ + col] =
            *(const bf16x8*)(qkv + qbase + 512 + (size_t)(kt * 64 + r) * 1536 + col);
      }
      __syncthreads();
      f32x4 acc[4] = {};
      #pragma unroll
      for (int kk = 0; kk < 2; kk++) {
        bf16x8 aq = *(const bf16x8*)&Qs[(w * 16 + l) * QS_ + kk * 32 + 8 * g];
        #pragma unroll
        for (int n = 0; n < 4; n++) {
          bf16x8 bk = *(const bf16x8*)&Ks[(n * 16 + l) * QS_ + kk * 32 + 8 * g];
          acc[n] = __builtin_amdgcn_mfma_f32_16x16x32_bf16(aq, bk, acc[n], 0, 0, 0);
        }
      }
      const bool diag = (kt == qt);
      #pragma unroll
      for (int j = 0; j < 4; j++) {
        int qloc = w * 16 + 4 * g + j;
        float sv[4];
        #pragma unroll
        for (int n = 0; n < 4; n++) {
          float v = acc[n][j] * 0.125f;
          if (diag && (n * 16 + l > qloc)) v = -3e38f;
          sv[n] = v;
        }
        float rm = fmaxf(fmaxf(sv[0], sv[1]), fmaxf(sv[2], sv[3]));
        #pragma unroll
        for (int mk = 1; mk < 16; mk <<= 1) rm = fmaxf(rm, __shfl_xor(rm, mk));
        float nm = fmaxf(mrow[j], rm);
        float fac = __expf(mrow[j] - nm);
        mrow[j] = nm;
        float ps = 0.f;
        #pragma unroll
        for (int n = 0; n < 4; n++) ps += __expf(sv[n] - nm);
        #pragma unroll
        for (int mk = 1; mk < 16; mk <<= 1) ps += __shfl_xor(ps, mk);
        lrow[j] = lrow[j] * fac + ps;
      }
    }
  }

  float invl[4];
  if (MODE == 1) {
    #pragma unroll
    for (int j = 0; j < 4; j++) invl[j] = 1.0f / lrow[j];
  }

  // main loop (MODE 0: online flash; MODE 1: pass 2 with known m,l)
  for (int kt = 0; kt <= qt; kt++) {
    __syncthreads();
    #pragma unroll
    for (int p = 0; p < 2; p++) {
      int c = p * 256 + tid; int r = c >> 3, col = (c & 7) * 8;
      *(bf16x8*)&Ks[r * QS_ + col] =
          *(const bf16x8*)(qkv + qbase + 512 + (size_t)(kt * 64 + r) * 1536 + col);
    }
    #pragma unroll
    for (int p = 0; p < 2; p++) {
      int c = p * 256 + tid; int key = c & 63, d0 = (c >> 6) * 8;
      bf16x8 vv = *(const bf16x8*)(qkv + qbase + 1024 + (size_t)(kt * 64 + key) * 1536 + d0);
      #pragma unroll
      for (int j = 0; j < 8; j++) Vt[(d0 + j) * PS_ + key] = (ushort)vv[j];
    }
    __syncthreads();

    f32x4 acc[4] = {};
    #pragma unroll
    for (int kk = 0; kk < 2; kk++) {
      bf16x8 aq = *(const bf16x8*)&Qs[(w * 16 + l) * QS_ + kk * 32 + 8 * g];
      #pragma unroll
      for (int n = 0; n < 4; n++) {
        bf16x8 bk = *(const bf16x8*)&Ks[(n * 16 + l) * QS_ + kk * 32 + 8 * g];
        acc[n] = __builtin_amdgcn_mfma_f32_16x16x32_bf16(aq, bk, acc[n], 0, 0, 0);
      }
    }
    const bool diag = (kt == qt);

    #pragma unroll
    for (int j = 0; j < 4; j++) {
      int qloc = w * 16 + 4 * g + j;
      float sv[4];
      #pragma unroll
      for (int n = 0; n < 4; n++) {
        float v = acc[n][j] * 0.125f;
        if (diag && (n * 16 + l > qloc)) v = -3e38f;
        sv[n] = v;
      }
      if (MODE == 0) {
        float rm = fmaxf(fmaxf(sv[0], sv[1]), fmaxf(sv[2], sv[3]));
        #pragma unroll
        for (int mk = 1; mk < 16; mk <<= 1) rm = fmaxf(rm, __shfl_xor(rm, mk));
        float nm = fmaxf(mrow[j], rm);
        float fac = __expf(mrow[j] - nm);
        mrow[j] = nm;
        float ps = 0.f, pv[4];
        #pragma unroll
        for (int n = 0; n < 4; n++) { pv[n] = __expf(sv[n] - nm); ps += pv[n]; }
        #pragma unroll
        for (int mk = 1; mk < 16; mk <<= 1) ps += __shfl_xor(ps, mk);
        lrow[j] = lrow[j] * fac + ps;
        #pragma unroll
        for (int n = 0; n < 4; n++) oacc[n][j] *= fac;
        #pragma unroll
        for (int n = 0; n < 4; n++)
          Ps[(w * 16 + 4 * g + j) * PS_ + n * 16 + l] = f2bf(pv[n]);
      } else {
        #pragma unroll
        for (int n = 0; n < 4; n++) {
          float p = __expf(sv[n] - mrow[j]) * invl[j];
          Ps[(w * 16 + 4 * g + j) * PS_ + n * 16 + l] = f2bf(p);
        }
      }
    }

    if (MODE == 1) {
      __syncthreads();
      // coalesced normalized-p output (f32) from Ps
      #pragma unroll
      for (int i = 0; i < 4; i++) {
        int c = i * 256 + tid; int r = c >> 4, col = (c & 15) * 4;
        float4 o4;
        o4.x = bf2f(Ps[r * PS_ + col + 0]);
        o4.y = bf2f(Ps[r * PS_ + col + 1]);
        o4.z = bf2f(Ps[r * PS_ + col + 2]);
        o4.w = bf2f(Ps[r * PS_ + col + 3]);
        *(float4*)(pout + ((size_t)(b * H_ + h) * S_ + qt * 64 + r) * S_ + kt * 64 + col) = o4;
      }
    }

    // PV: O += P @ V   (A = Ps rows w*16+l, B = Vt [d][key])
    #pragma unroll
    for (int kk = 0; kk < 2; kk++) {
      bf16x8 pa = *(const bf16x8*)&Ps[(w * 16 + l) * PS_ + kk * 32 + 8 * g];
      #pragma unroll
      for (int n = 0; n < 4; n++) {
        bf16x8 vb = *(const bf16x8*)&Vt[(n * 16 + l) * PS_ + kk * 32 + 8 * g];
        oacc[n] = __builtin_amdgcn_mfma_f32_16x16x32_bf16(pa, vb, oacc[n], 0, 0, 0);
      }
    }
  }

  if (MODE == 1) {
    // zero tiles above the diagonal
    for (int kt = qt + 1; kt < 8; kt++) {
      #pragma unroll
      for (int i = 0; i < 4; i++) {
        int c = i * 256 + tid; int r = c >> 4, col = (c & 15) * 4;
        *(float4*)(pout + ((size_t)(b * H_ + h) * S_ + qt * 64 + r) * S_ + kt * 64 + col) =
            make_float4(0.f, 0.f, 0.f, 0.f);
      }
    }
  }

  // write O (bf16)
  #pragma unroll
  for (int j = 0; j < 4; j++) {
    float inv = (MODE == 0) ? 1.0f / lrow[j] : 1.0f;
    size_t rowoff = (size_t)(b * S_ + qt * 64 + w * 16 + 4 * g + j) * 512 + h * 64;
    #pragma unroll
    for (int n = 0; n < 4; n++)
      og[rowoff + n * 16 + l] = f2bf(oacc[n][j] * inv);
  }
}

// ---------------------------------------------------------------------------
__global__ __launch_bounds__(128) void embed_finish(float* __restrict__ h,
    const int* __restrict__ x, const float* __restrict__ cmd_emb,
    const float* __restrict__ cls_emb, const int* __restrict__ trg_char)
{
  int m = blockIdx.x, b = m >> 9, s = m & 511;
  int d = threadIdx.x << 2;
  float4* hp = (float4*)(h + (size_t)m * D_ + d);
  if (s == 0) {
    int c = trg_char[b];
    *hp = *(const float4*)(cls_emb + (size_t)c * D_ + d);
  } else {
    int cmd = x[(size_t)(s * B_ + b) * 9];
    float4 v  = *hp;
    float4 ce = *(const float4*)(cmd_emb + (size_t)cmd * D_ + d);
    const float kfac = -0.017988946039f;   // -ln(10000)/512
    int i0 = d >> 1;
    float ang0 = (float)s * expf((float)(2 * i0) * kfac);
    float ang1 = (float)s * expf((float)(2 * (i0 + 1)) * kfac);
    v.x += ce.x + sinf(ang0);
    v.y += ce.y + cosf(ang0);
    v.z += ce.z + sinf(ang1);
    v.w += ce.w + cosf(ang1);
    *hp = v;
  }
}

// ---------------------------------------------------------------------------
__global__ __launch_bounds__(256) void ca_stage(const float* __restrict__ in,
    const float* __restrict__ ca_w, const float* __restrict__ ca_b,
    float* __restrict__ outb, int wsel, int in_is_per_l)
{
  int l = blockIdx.x >> 5, b = blockIdx.x & 31;
  __shared__ float sm[512];
  const float* src = in_is_per_l ? in + ((size_t)l * 32 + b) * 512 : in + (size_t)b * 512;
  for (int i = threadIdx.x; i < 512; i += 256) sm[i] = src[i];
  __syncthreads();
  const float* Wl = ca_w + ((size_t)(l * 4 + wsel)) * 512 * 512;
  const float* bl = ca_b + (l * 4 + wsel) * 512;
  for (int n = threadIdx.x; n < 512; n += 256) {
    const float* wr = Wl + (size_t)n * 512;
    float acc = 0.f;
    for (int k2 = 0; k2 < 512; k2 += 4) {
      float4 w4 = *(const float4*)(wr + k2);
      acc += sm[k2] * w4.x + sm[k2+1] * w4.y + sm[k2+2] * w4.z + sm[k2+3] * w4.w;
    }
    outb[((size_t)l * 32 + b) * 512 + n] = acc + bl[n];
  }
}

__global__ __launch_bounds__(128) void add_ca(float* __restrict__ h,
    const float* __restrict__ ca)
{
  int m = blockIdx.x, b = m >> 9;
  int d = threadIdx.x << 2;
  float4* hp = (float4*)(h + (size_t)m * D_ + d);
  float4 v = *hp;
  float4 c = *(const float4*)(ca + (size_t)b * D_ + d);
  v.x += c.x; v.y += c.y; v.z += c.z; v.w += c.w;
  *hp = v;
}

__global__ __launch_bounds__(256) void cmd_head(const ushort* __restrict__ xn,
    const float* __restrict__ cw, const float* __restrict__ cb, float* __restrict__ out)
{
  int row  = (blockIdx.x << 2) + (threadIdx.x >> 6);
  int lane = threadIdx.x & 63;
  uint4 raw = *(const uint4*)(xn + (size_t)row * D_ + lane * 8);
  float x0 = bf2f(raw.x & 0xffff), x1 = bf2f(raw.x >> 16);
  float x2 = bf2f(raw.y & 0xffff), x3 = bf2f(raw.y >> 16);
  float x4 = bf2f(raw.z & 0xffff), x5 = bf2f(raw.z >> 16);
  float x6 = bf2f(raw.w & 0xffff), x7 = bf2f(raw.w >> 16);
  #pragma unroll
  for (int n = 0; n < 4; n++) {
    const float* w = cw + n * 512 + lane * 8;
    float4 w0 = *(const float4*)w, w1 = *(const float4*)(w + 4);
    float p = x0*w0.x + x1*w0.y + x2*w0.z + x3*w0.w
            + x4*w1.x + x5*w1.y + x6*w1.z + x7*w1.w;
    #pragma unroll
    for (int m = 1; m < 64; m <<= 1) p += __shfl_xor(p, m);
    if (lane == 0) out[(size_t)row * 4 + n] = p + cb[n];
  }
}

// ---------------------------------------------------------------------------
extern "C" void kernel_launch(void* const* d_in, const int* in_sizes, int n_in,
                              void* d_out, int out_size, void* d_ws, size_t ws_size,
                              hipStream_t stream)
{
  const int*   x          = (const int*)  d_in[0];
  const float* memory     = (const float*)d_in[1];
  const int*   trg_char   = (const int*)  d_in[2];
  const float* cmd_emb    = (const float*)d_in[4];
  const float* arg_emb    = (const float*)d_in[5];
  const float* embed_w    = (const float*)d_in[6];
  const float* embed_b    = (const float*)d_in[7];
  const float* sa_w       = (const float*)d_in[8];
  const float* sa_b       = (const float*)d_in[9];
  const float* ca_w       = (const float*)d_in[10];
  const float* ca_b       = (const float*)d_in[11];
  const float* ff_w1      = (const float*)d_in[12];
  const float* ff_b1      = (const float*)d_in[13];
  const float* ff_w2      = (const float*)d_in[14];
  const float* ff_b2      = (const float*)d_in[15];
  const float* ln_g       = (const float*)d_in[16];
  const float* ln_b       = (const float*)d_in[17];
  const float* fn_g       = (const float*)d_in[18];
  const float* fn_b       = (const float*)d_in[19];
  const float* cls_emb    = (const float*)d_in[20];
  const float* cmd_w      = (const float*)d_in[21];
  const float* cmd_b      = (const float*)d_in[22];
  const float* argf_w     = (const float*)d_in[23];
  const float* argf_b     = (const float*)d_in[24];

  float* out_cmd  = (float*)d_out;
  float* out_args = out_cmd + (size_t)M_ * 4;
  float* out_attn = out_args + (size_t)M_ * 1024;

  const size_t MS = (size_t)M_ * D_;     // 8388608
  float* ws = (float*)d_ws;
  float*  h      = ws;                                   // MS f32
  ushort* qkv_bf = (ushort*)(ws + MS);                   // M*1536 bf16
  ushort* xn_bf  = (ushort*)(ws + MS + 12582912);        // M*512
  ushort* o_bf   = (ushort*)(ws + MS + 16777216);        // M*512
  ushort* tA_bf  = (ushort*)(ws + MS + 20971520);        // M*1024
  ushort* wbf    = (ushort*)(ws + MS + 29360128);
  ushort* sa_wb   = wbf;                                 // 6291456
  ushort* ff1_wb  = wbf + 6291456;                       // 3145728
  ushort* ff2_wb  = wbf + 9437184;                       // 3145728
  ushort* emb_wb  = wbf + 12582912;                      // 524288
  ushort* argf_wb = wbf + 13107200;                      // 524288
  float* vvec   = ws + MS + 29360128 + 6815744;
  float* ca_out = vvec + 6 * 32 * 512;

  dim3 blk256(256), blk128(128);
  dim3 g_g512(4, 128);
  dim3 g_g1024(8, 128);
  dim3 g_g1536(12, 128);
  dim3 g_ln(M_ / 4);
  dim3 g_attn(8, H_, B_);
  dim3 g_row(M_);

  cvt_bf16<<<dim3(3072), blk256, 0, stream>>>(sa_w,   sa_wb,   786432);
  cvt_bf16<<<dim3(1536), blk256, 0, stream>>>(ff_w1,  ff1_wb,  393216);
  cvt_bf16<<<dim3(1536), blk256, 0, stream>>>(ff_w2,  ff2_wb,  393216);
  cvt_bf16<<<dim3(256),  blk256, 0, stream>>>(embed_w, emb_wb,  65536);
  cvt_bf16<<<dim3(256),  blk256, 0, stream>>>(argf_w, argf_wb,  65536);

  ca_stage<<<dim3(L_ * 32), blk256, 0, stream>>>(memory, ca_w, ca_b, vvec, 2, 0);
  ca_stage<<<dim3(L_ * 32), blk256, 0, stream>>>(vvec, ca_w, ca_b, ca_out, 3, 1);

  gather_emb<<<dim3(8192), blk256, 0, stream>>>(x, arg_emb, tA_bf);
  gemm_mfma<0><<<g_g512, blk256, 0, stream>>>(tA_bf, emb_wb, embed_b, h, M_, D_, 1024);
  embed_finish<<<g_row, blk128, 0, stream>>>(h, x, cmd_emb, cls_emb, trg_char);

  for (int l = 0; l < L_; l++) {
    const ushort* saW = sa_wb + (size_t)l * 4 * D_ * D_;
    const float*  saB = sa_b + (size_t)l * 4 * D_;
    ln_bf<<<g_ln, blk256, 0, stream>>>(h, xn_bf, ln_g + (l * 3 + 0) * D_, ln_b + (l * 3 + 0) * D_);
    // fused QKV projection: W rows [0..1535] = w0|w1|w2 (contiguous), bias b0|b1|b2
    gemm_mfma<3><<<g_g1536, blk256, 0, stream>>>(xn_bf, saW, saB, qkv_bf, M_, 1536, D_);
    if (l == L_ - 1)
      attn_mfma<1><<<g_attn, blk256, 0, stream>>>(qkv_bf, o_bf, out_attn);
    else
      attn_mfma<0><<<g_attn, blk256, 0, stream>>>(qkv_bf, o_bf, nullptr);
    gemm_mfma<2><<<g_g512, blk256, 0, stream>>>(o_bf, saW + (size_t)3*D_*D_, saB + 3*D_, h, M_, D_, D_);
    add_ca<<<g_row, blk128, 0, stream>>>(h, ca_out + (size_t)l * 32 * D_);
    ln_bf<<<g_ln, blk256, 0, stream>>>(h, xn_bf, ln_g + (l * 3 + 2) * D_, ln_b + (l * 3 + 2) * D_);
    gemm_mfma<1><<<g_g1024, blk256, 0, stream>>>(xn_bf, ff1_wb + (size_t)l*DFF_*D_, ff_b1 + l*DFF_, tA_bf, M_, DFF_, D_);
    gemm_mfma<2><<<g_g512,  blk256, 0, stream>>>(tA_bf, ff2_wb + (size_t)l*D_*DFF_, ff_b2 + l*D_,   h,     M_, D_, DFF_);
  }

  ln_bf<<<g_ln, blk256, 0, stream>>>(h, xn_bf, fn_g, fn_b);
  gemm_mfma<0><<<g_g1024, blk256, 0, stream>>>(xn_bf, argf_wb, argf_b, out_args, M_, 1024, D_);
  cmd_head<<<dim3(M_ / 4), blk256, 0, stream>>>(xn_bf, cmd_w, cmd_b, out_cmd);
}